// Round 13
// baseline (322.759 us; speedup 1.0000x reference)
//
#include <hip/hip_runtime.h>

// GraphSAGE 2-layer, N=100000, E=1600000, 128 -> 64 -> 32.
// Round 13: CSR build restructured as bucket-partition + chunk-local fill.
// Round-12 evidence: dst-chunked fill re-reads the 12.8MB edge stream 8x
// (FETCH 50MB) and that stream evicts the 800KB csr window from L2 before
// lines fill (WRITE stuck at 67-72MB; NT loads made it worse by bypassing
// L3). New: (1) bucket_edges reads edges ONCE, partitions into 8 dst-chunk
// buckets with LDS histogram + block reservations -> sequential merged
// writes; (2) count_deg_b/fill_csr_b (chunk = blockIdx&7, XCD-aligned) read
// only their 1.6MB bucket -> working set ~2.5MB << 4MB L2 -> csr writes
// merge. bf16 z kept (absmax 0.0078 unchanged). Everything else identical.

namespace {
constexpr int N = 100000;
constexpr int E = 1600000;
constexpr int NBLK = (N + 255) / 256;           // 391 scan blocks
constexpr int NT16 = N / 16;                    // 6250 node tiles (exact)
constexpr int NCHUNK = 8;                       // 12500 nodes per chunk
constexpr int CHUNK_N = N / NCHUNK;
constexpr int BPC = 128;                        // blocks per chunk
constexpr int CAP = E / NCHUNK + 8192;          // bucket capacity (208192)
constexpr int PA_BLOCKS = 256;
constexpr int PER_BLK = E / PA_BLOCKS;          // 6250 edges per block
}

using bf16x8 = __attribute__((ext_vector_type(8))) short;
using f32x4  = __attribute__((ext_vector_type(4))) float;

__device__ __forceinline__ short f2bf(float f) {
    unsigned u = __builtin_bit_cast(unsigned, f);
    u += 0x7FFFu + ((u >> 16) & 1u);            // RNE truncate to bf16
    return (short)(u >> 16);
}

__device__ __forceinline__ float bf2f(unsigned short u) {
    return __builtin_bit_cast(float, (unsigned)u << 16);
}

__device__ __forceinline__ bf16x8 load_frag8(const float* __restrict__ p) {
    const float4* p4 = (const float4*)p;
    float4 f0 = p4[0], f1 = p4[1];
    bf16x8 r;
    r[0] = f2bf(f0.x); r[1] = f2bf(f0.y); r[2] = f2bf(f0.z); r[3] = f2bf(f0.w);
    r[4] = f2bf(f1.x); r[5] = f2bf(f1.y); r[6] = f2bf(f1.z); r[7] = f2bf(f1.w);
    return r;
}

// ---------------- CSR build ----------------

// int64 vs int32 edge dtype: sample 16384 high words, single block, one store.
__global__ __launch_bounds__(256) void detect_dtype(const int* __restrict__ raw,
                                                    int* __restrict__ flag) {
    int any = 0;
#pragma unroll
    for (int k = 0; k < 64; ++k) {
        int i = threadIdx.x + k * 256;          // first 16384 qwords
        any |= raw[2 * i + 1];
    }
    unsigned long long b = __ballot(any != 0);
    __shared__ int acc[4];
    int w = threadIdx.x >> 6;
    if ((threadIdx.x & 63) == 0) acc[w] = (b != 0ULL) ? 1 : 0;
    __syncthreads();
    if (threadIdx.x == 0) *flag = acc[0] | acc[1] | acc[2] | acc[3];
}

__global__ void zero_counts(int* __restrict__ counts, int* __restrict__ bcur) {
    int i = blockIdx.x * blockDim.x + threadIdx.x;
    if (i < N) counts[i] = 0;
    if (i < NCHUNK) bcur[i] = 0;
}

// Partition edges into 8 dst-chunk buckets. One sequential read of the edge
// stream; per-block LDS histogram -> one global reservation per chunk ->
// grouped sequential writes (merge in L2).
__global__ __launch_bounds__(256) void bucket_edges(
        const int* __restrict__ raw, const int* __restrict__ flag,
        int* __restrict__ bcur, int2* __restrict__ bucket) {
    __shared__ int cnt[NCHUNK];
    __shared__ int res[NCHUNK];
    if (threadIdx.x < NCHUNK) cnt[threadIdx.x] = 0;
    __syncthreads();
    const int is32 = *flag;
    const int e0 = blockIdx.x * PER_BLK;
    for (int i = threadIdx.x; i < PER_BLK; i += 256) {
        int e = e0 + i;
        int d = is32 ? raw[E + e] : raw[2 * ((long long)E + e)];
        atomicAdd(&cnt[d / CHUNK_N], 1);
    }
    __syncthreads();
    if (threadIdx.x < NCHUNK) {
        res[threadIdx.x] = atomicAdd(&bcur[threadIdx.x], cnt[threadIdx.x]);
        cnt[threadIdx.x] = 0;
    }
    __syncthreads();
    for (int i = threadIdx.x; i < PER_BLK; i += 256) {
        int e = e0 + i;
        int d, s;
        if (is32) { d = raw[E + e]; s = raw[e]; }
        else      { d = raw[2 * ((long long)E + e)]; s = raw[2 * (long long)e]; }
        int c = d / CHUNK_N;
        int pos = res[c] + atomicAdd(&cnt[c], 1);
        if (pos < CAP) bucket[(size_t)c * CAP + pos] = make_int2(s, d);
    }
}

// Degree histogram from buckets, chunk-local (counts window 50KB on one L2).
__global__ __launch_bounds__(256) void count_deg_b(
        const int* __restrict__ bcur, const int2* __restrict__ bucket,
        int* __restrict__ counts) {
    const int chunk = blockIdx.x & (NCHUNK - 1);
    const int bsl   = blockIdx.x >> 3;
    int n = bcur[chunk]; if (n > CAP) n = CAP;
    const int2* b = bucket + (size_t)chunk * CAP;
    for (int i = bsl * 256 + threadIdx.x; i < n; i += BPC * 256)
        atomicAdd(&counts[b[i].y], 1);
}

// Block-local inclusive scan (Hillis-Steele over 256 entries in LDS).
__global__ __launch_bounds__(256) void scan1(const int* __restrict__ counts,
                                             int* __restrict__ rowstart,
                                             int* __restrict__ bsum) {
    __shared__ int tmp[256];
    int t = threadIdx.x;
    int i = blockIdx.x * 256 + t;
    int v = (i < N) ? counts[i] : 0;
    tmp[t] = v;
    __syncthreads();
#pragma unroll
    for (int off = 1; off < 256; off <<= 1) {
        int a = (t >= off) ? tmp[t - off] : 0;
        __syncthreads();
        tmp[t] += a;
        __syncthreads();
    }
    if (i < N) rowstart[i] = tmp[t] - v;          // exclusive within block
    if (t == 255) bsum[blockIdx.x] = tmp[255];    // block total
}

__global__ __launch_bounds__(512) void scan2(int* __restrict__ bsum) {
    __shared__ int tmp[512];
    int t = threadIdx.x;
    int v = (t < NBLK) ? bsum[t] : 0;
    tmp[t] = v;
    __syncthreads();
#pragma unroll
    for (int off = 1; off < 512; off <<= 1) {
        int a = (t >= off) ? tmp[t - off] : 0;
        __syncthreads();
        tmp[t] += a;
        __syncthreads();
    }
    if (t < NBLK) bsum[t] = tmp[t] - v;           // exclusive block offsets
}

__global__ void scan3(int* __restrict__ rowstart, const int* __restrict__ bsum,
                      int* __restrict__ cursor) {
    int i = blockIdx.x * blockDim.x + threadIdx.x;
    if (i < N) {
        rowstart[i] += bsum[i >> 8];
        cursor[i] = 0;                            // counts recycled as cursor
    }
    if (i == 0) rowstart[N] = E;
}

// CSR fill from buckets, chunk-local, XCD-aligned: working set = 1.6MB bucket
// (sequential) + 800KB csr window + 50KB cursor -> fits one L2, writes merge.
__global__ __launch_bounds__(256) void fill_csr_b(
        const int* __restrict__ bcur, const int2* __restrict__ bucket,
        const int* __restrict__ rowstart, int* __restrict__ cursor,
        int* __restrict__ csr) {
    const int chunk = blockIdx.x & (NCHUNK - 1);
    const int bsl   = blockIdx.x >> 3;
    int n = bcur[chunk]; if (n > CAP) n = CAP;
    const int2* b = bucket + (size_t)chunk * CAP;
    for (int i = bsl * 256 + threadIdx.x; i < n; i += BPC * 256) {
        int2 sd = b[i];
        int pos = rowstart[sd.y] + atomicAdd(&cursor[sd.y], 1);
        csr[pos] = sd.x;
    }
}

// ---------------- layer 1 transform (MFMA): z1(bf16) = x@W1l^T, r1(f32) = x@W1r^T ----------------
__global__ __launch_bounds__(256) void transform1_mfma(
        const float* __restrict__ x, const float* __restrict__ W1l,
        const float* __restrict__ W1r, unsigned short* __restrict__ z1b,
        float* __restrict__ r1) {
    const int lane = threadIdx.x & 63;
    const int gw = blockIdx.x * 4 + (threadIdx.x >> 6);
    const int q = gw & 1;
    const int r16 = lane & 15;
    const int kgrp = lane >> 4;                  // 0..3

    bf16x8 wf[2][2][4];                          // [mat][coltile][kb]
#pragma unroll
    for (int m = 0; m < 2; ++m) {
        const float* W = m ? W1r : W1l;
#pragma unroll
        for (int c = 0; c < 2; ++c) {
            const float* pw = W + (size_t)(q * 32 + c * 16 + r16) * 128 + kgrp * 8;
#pragma unroll
            for (int kb = 0; kb < 4; ++kb)
                wf[m][c][kb] = load_frag8(pw + kb * 32);
        }
    }

    const int stride = (gridDim.x * 4) >> 1;
    for (int t = gw >> 1; t < NT16; t += stride) {
        const float* px = x + ((size_t)t * 16 + r16) * 128 + kgrp * 8;
        bf16x8 af[4];
#pragma unroll
        for (int kb = 0; kb < 4; ++kb) af[kb] = load_frag8(px + kb * 32);

        f32x4 a00 = {0.f,0.f,0.f,0.f}, a01 = {0.f,0.f,0.f,0.f};
        f32x4 a10 = {0.f,0.f,0.f,0.f}, a11 = {0.f,0.f,0.f,0.f};
#pragma unroll
        for (int kb = 0; kb < 4; ++kb) {
            a00 = __builtin_amdgcn_mfma_f32_16x16x32_bf16(af[kb], wf[0][0][kb], a00, 0, 0, 0);
            a01 = __builtin_amdgcn_mfma_f32_16x16x32_bf16(af[kb], wf[0][1][kb], a01, 0, 0, 0);
            a10 = __builtin_amdgcn_mfma_f32_16x16x32_bf16(af[kb], wf[1][0][kb], a10, 0, 0, 0);
            a11 = __builtin_amdgcn_mfma_f32_16x16x32_bf16(af[kb], wf[1][1][kb], a11, 0, 0, 0);
        }
#pragma unroll
        for (int i = 0; i < 4; ++i) {
            size_t row = (size_t)t * 16 + kgrp * 4 + i;
            z1b[row * 64 + q * 32 +  0 + r16] = (unsigned short)f2bf(a00[i]);
            z1b[row * 64 + q * 32 + 16 + r16] = (unsigned short)f2bf(a01[i]);
            r1[row * 64 + q * 32 +  0 + r16] = a10[i];
            r1[row * 64 + q * 32 + 16 + r16] = a11[i];
        }
    }
}

// ---------------- layer 2 transform (MFMA): z2(bf16) = h@W2l^T, r2(f32) = h@W2r^T ----------------
__global__ __launch_bounds__(256) void transform2_mfma(
        const float* __restrict__ h, const float* __restrict__ W2l,
        const float* __restrict__ W2r, unsigned short* __restrict__ z2b,
        float* __restrict__ r2) {
    const int lane = threadIdx.x & 63;
    const int gw = blockIdx.x * 4 + (threadIdx.x >> 6);
    const int r16 = lane & 15;
    const int kgrp = lane >> 4;

    bf16x8 wf[2][2][2];                          // [mat][coltile][kb]
#pragma unroll
    for (int m = 0; m < 2; ++m) {
        const float* W = m ? W2r : W2l;
#pragma unroll
        for (int c = 0; c < 2; ++c) {
            const float* pw = W + (size_t)(c * 16 + r16) * 64 + kgrp * 8;
#pragma unroll
            for (int kb = 0; kb < 2; ++kb)
                wf[m][c][kb] = load_frag8(pw + kb * 32);
        }
    }

    for (int t = gw; t < NT16; t += gridDim.x * 4) {
        const float* ph = h + ((size_t)t * 16 + r16) * 64 + kgrp * 8;
        bf16x8 af[2];
        af[0] = load_frag8(ph);
        af[1] = load_frag8(ph + 32);

        f32x4 a00 = {0.f,0.f,0.f,0.f}, a01 = {0.f,0.f,0.f,0.f};
        f32x4 a10 = {0.f,0.f,0.f,0.f}, a11 = {0.f,0.f,0.f,0.f};
#pragma unroll
        for (int kb = 0; kb < 2; ++kb) {
            a00 = __builtin_amdgcn_mfma_f32_16x16x32_bf16(af[kb], wf[0][0][kb], a00, 0, 0, 0);
            a01 = __builtin_amdgcn_mfma_f32_16x16x32_bf16(af[kb], wf[0][1][kb], a01, 0, 0, 0);
            a10 = __builtin_amdgcn_mfma_f32_16x16x32_bf16(af[kb], wf[1][0][kb], a10, 0, 0, 0);
            a11 = __builtin_amdgcn_mfma_f32_16x16x32_bf16(af[kb], wf[1][1][kb], a11, 0, 0, 0);
        }
#pragma unroll
        for (int i = 0; i < 4; ++i) {
            size_t row = (size_t)t * 16 + kgrp * 4 + i;
            z2b[row * 32 +  0 + r16] = (unsigned short)f2bf(a00[i]);
            z2b[row * 32 + 16 + r16] = (unsigned short)f2bf(a01[i]);
            r2[row * 32 +  0 + r16] = a10[i];
            r2[row * 32 + 16 + r16] = a11[i];
        }
    }
}

// ---------------- fused CSR-gather aggregation ----------------

// Layer 1: wave per node, lane = feature j (64 feats), bf16 z gather.
__global__ __launch_bounds__(256) void agg1_fused(
        const int* __restrict__ rowstart, const int* __restrict__ csr,
        const unsigned short* __restrict__ z1b, const float* __restrict__ r1,
        const float* __restrict__ b1, float* __restrict__ h) {
    const int n = blockIdx.x * 4 + (threadIdx.x >> 6);
    if (n >= N) return;
    const int j = threadIdx.x & 63;
    const int beg = rowstart[n], end = rowstart[n + 1];
    float s = 0.f;
    int p = beg;
    for (; p + 4 <= end; p += 4) {
        int c0 = csr[p], c1 = csr[p + 1], c2 = csr[p + 2], c3 = csr[p + 3];
        s += bf2f(z1b[(size_t)c0 * 64 + j]) + bf2f(z1b[(size_t)c1 * 64 + j])
           + bf2f(z1b[(size_t)c2 * 64 + j]) + bf2f(z1b[(size_t)c3 * 64 + j]);
    }
    for (; p < end; ++p) s += bf2f(z1b[(size_t)csr[p] * 64 + j]);
    float m = (end > beg) ? s / (float)(end - beg) : 0.f;
    size_t o = (size_t)n * 64 + j;
    h[o] = fmaxf(m + b1[j] + r1[o], 0.f);
}

// Layer 2: half-wave per node (32 feats), wave handles 2 nodes.
__global__ __launch_bounds__(256) void agg2_fused(
        const int* __restrict__ rowstart, const int* __restrict__ csr,
        const unsigned short* __restrict__ z2b, const float* __restrict__ r2,
        const float* __restrict__ b2, float* __restrict__ out) {
    const int wid = blockIdx.x * 4 + (threadIdx.x >> 6);
    const int n = wid * 2 + ((threadIdx.x >> 5) & 1);
    if (n >= N) return;
    const int j = threadIdx.x & 31;
    const int beg = rowstart[n], end = rowstart[n + 1];
    float s = 0.f;
    int p = beg;
    for (; p + 4 <= end; p += 4) {
        int c0 = csr[p], c1 = csr[p + 1], c2 = csr[p + 2], c3 = csr[p + 3];
        s += bf2f(z2b[(size_t)c0 * 32 + j]) + bf2f(z2b[(size_t)c1 * 32 + j])
           + bf2f(z2b[(size_t)c2 * 32 + j]) + bf2f(z2b[(size_t)c3 * 32 + j]);
    }
    for (; p < end; ++p) s += bf2f(z2b[(size_t)csr[p] * 32 + j]);
    float m = (end > beg) ? s / (float)(end - beg) : 0.f;
    size_t o = (size_t)n * 32 + j;
    out[o] = m + b2[j] + r2[o];
}

// ---------------- launch ----------------

extern "C" void kernel_launch(void* const* d_in, const int* in_sizes, int n_in,
                              void* d_out, int out_size, void* d_ws, size_t ws_size,
                              hipStream_t stream) {
    const float* x    = (const float*)d_in[0];
    const int*   raw  = (const int*)d_in[1];
    const float* W1l  = (const float*)d_in[2];
    const float* b1   = (const float*)d_in[3];
    const float* W1r  = (const float*)d_in[4];
    const float* W2l  = (const float*)d_in[5];
    const float* b2   = (const float*)d_in[6];
    const float* W2r  = (const float*)d_in[7];
    float* out = (float*)d_out;

    // byte-offset workspace layout
    char* wsb = (char*)d_ws;
    unsigned short* z1b = (unsigned short*)wsb;              // [N*64] bf16 (12.8MB)
    unsigned short* z2b = (unsigned short*)wsb;              // [N*32] overlays z1b
    float* r1 = (float*)(wsb + 16 * 1024 * 1024);            // [N*64] f32 (25.6MB)
    float* r2 = (float*)(wsb + 16 * 1024 * 1024);            // [N*32] overlays r1
    float* h  = (float*)(wsb + 48 * 1024 * 1024);            // [N*64] f32 (25.6MB)
    int2* bucket = (int2*)(wsb + 48 * 1024 * 1024);          // 8 x CAP x 8B (13.3MB)
    // bucket overlays h: buckets die before agg1_fused writes h.

    int* ibase    = (int*)(wsb + 80 * 1024 * 1024);
    int* counts   = ibase;                   // [N], recycled as cursor
    int* rowstart = ibase + N;               // [N+1]
    int* bsum     = ibase + 2 * N + 1;       // [512]
    int* csr      = ibase + 2 * N + 1 + 512; // [E]
    int* flag     = csr + E;                 // [1]
    int* bcur     = flag + 1;                // [8]

    detect_dtype<<<1, 256, 0, stream>>>(raw, flag);
    zero_counts<<<NBLK, 256, 0, stream>>>(counts, bcur);
    bucket_edges<<<PA_BLOCKS, 256, 0, stream>>>(raw, flag, bcur, bucket);
    count_deg_b<<<NCHUNK * BPC, 256, 0, stream>>>(bcur, bucket, counts);
    scan1<<<NBLK, 256, 0, stream>>>(counts, rowstart, bsum);
    scan2<<<1, 512, 0, stream>>>(bsum);
    scan3<<<NBLK, 256, 0, stream>>>(rowstart, bsum, counts);
    fill_csr_b<<<NCHUNK * BPC, 256, 0, stream>>>(bcur, bucket, rowstart, counts, csr);

    transform1_mfma<<<1024, 256, 0, stream>>>(x, W1l, W1r, z1b, r1);
    agg1_fused<<<(N + 3) / 4, 256, 0, stream>>>(rowstart, csr, z1b, r1, b1, h);

    transform2_mfma<<<1024, 256, 0, stream>>>(h, W2l, W2r, z2b, r2);
    agg2_fused<<<(N + 7) / 8, 256, 0, stream>>>(rowstart, csr, z2b, r2, b2, out);
}

// Round 14
// 224.524 us; speedup vs baseline: 1.4375x; 1.4375x over previous
//
#include <hip/hip_runtime.h>

// GraphSAGE 2-layer, N=100000, E=1600000, 128 -> 64 -> 32.
// Round 14: CSR build via 64-chunk counting sort with ONE BLOCK PER CHUNK and
// LDS cursors. Rounds 9-13 evidence: random global 4B stores + global cursor
// atomics never merge (WRITE stuck at 67-107MB regardless of chunking/XCD
// alignment/NT hints). New fill2/count2: per-chunk block streams its bucket
// sequentially, ranks via LDS atomics (no global atomics), writes its 100KB
// csr window from a single CU -> single L2 -> full line accumulation.
// Kills count_deg_b, zero_counts, scan3's cursor pass. bf16 z kept.
// Transforms + aggs byte-identical to round 13 (agg1 unroll 4->8 only).

namespace {
constexpr int N = 100000;
constexpr int E = 1600000;
constexpr int NBLK = (N + 255) / 256;           // 391 scan blocks
constexpr int NT16 = N / 16;                    // 6250 node tiles (exact)
constexpr int NCHUNK = 64;                      // 1600 nodes per chunk
constexpr int CHUNK_N = 1600;                   // 64*1600 = 102400 >= N
constexpr int CAP = 28000;                      // bucket capacity (mean 25600, ~15 sigma)
constexpr int PA_BLOCKS = 256;
constexpr int PER_BLK = E / PA_BLOCKS;          // 6250 edges per block
}

using bf16x8 = __attribute__((ext_vector_type(8))) short;
using f32x4  = __attribute__((ext_vector_type(4))) float;

__device__ __forceinline__ short f2bf(float f) {
    unsigned u = __builtin_bit_cast(unsigned, f);
    u += 0x7FFFu + ((u >> 16) & 1u);            // RNE truncate to bf16
    return (short)(u >> 16);
}

__device__ __forceinline__ float bf2f(unsigned short u) {
    return __builtin_bit_cast(float, (unsigned)u << 16);
}

__device__ __forceinline__ bf16x8 load_frag8(const float* __restrict__ p) {
    const float4* p4 = (const float4*)p;
    float4 f0 = p4[0], f1 = p4[1];
    bf16x8 r;
    r[0] = f2bf(f0.x); r[1] = f2bf(f0.y); r[2] = f2bf(f0.z); r[3] = f2bf(f0.w);
    r[4] = f2bf(f1.x); r[5] = f2bf(f1.y); r[6] = f2bf(f1.z); r[7] = f2bf(f1.w);
    return r;
}

// ---------------- CSR build ----------------

// int64 vs int32 edge dtype (sample 16384 high words) + zero bucket cursors.
__global__ __launch_bounds__(256) void detect_dtype(const int* __restrict__ raw,
                                                    int* __restrict__ flag,
                                                    int* __restrict__ bcur) {
    if (threadIdx.x < NCHUNK) bcur[threadIdx.x] = 0;
    int any = 0;
#pragma unroll
    for (int k = 0; k < 64; ++k) {
        int i = threadIdx.x + k * 256;          // first 16384 qwords
        any |= raw[2 * i + 1];
    }
    unsigned long long b = __ballot(any != 0);
    __shared__ int acc[4];
    int w = threadIdx.x >> 6;
    if ((threadIdx.x & 63) == 0) acc[w] = (b != 0ULL) ? 1 : 0;
    __syncthreads();
    if (threadIdx.x == 0) *flag = acc[0] | acc[1] | acc[2] | acc[3];
}

// Partition edges into 64 dst-chunk buckets. One sequential read of the edge
// stream; per-block LDS histogram -> one global reservation per chunk ->
// grouped writes (runs of ~100 int2 per chunk per block).
__global__ __launch_bounds__(256) void bucket_edges(
        const int* __restrict__ raw, const int* __restrict__ flag,
        int* __restrict__ bcur, int2* __restrict__ bucket) {
    __shared__ int cnt[NCHUNK];
    __shared__ int res[NCHUNK];
    if (threadIdx.x < NCHUNK) cnt[threadIdx.x] = 0;
    __syncthreads();
    const int is32 = *flag;
    const int e0 = blockIdx.x * PER_BLK;
    for (int i = threadIdx.x; i < PER_BLK; i += 256) {
        int e = e0 + i;
        int d = is32 ? raw[E + e] : raw[2 * ((long long)E + e)];
        atomicAdd(&cnt[d / CHUNK_N], 1);
    }
    __syncthreads();
    if (threadIdx.x < NCHUNK) {
        res[threadIdx.x] = atomicAdd(&bcur[threadIdx.x], cnt[threadIdx.x]);
        cnt[threadIdx.x] = 0;
    }
    __syncthreads();
    for (int i = threadIdx.x; i < PER_BLK; i += 256) {
        int e = e0 + i;
        int d, s;
        if (is32) { d = raw[E + e]; s = raw[e]; }
        else      { d = raw[2 * ((long long)E + e)]; s = raw[2 * (long long)e]; }
        int c = d / CHUNK_N;
        int pos = res[c] + atomicAdd(&cnt[c], 1);
        if (pos < CAP) bucket[(size_t)c * CAP + pos] = make_int2(s, d);
    }
}

// Per-chunk degree count: one block per chunk, LDS counters, sequential
// bucket read, sequential counts write. No global atomics.
__global__ __launch_bounds__(1024) void count2(
        const int* __restrict__ bcur, const int2* __restrict__ bucket,
        int* __restrict__ counts) {
    __shared__ int scnt[CHUNK_N];
    const int chunk = blockIdx.x;
    const int lo = chunk * CHUNK_N;
    for (int i = threadIdx.x; i < CHUNK_N; i += 1024) scnt[i] = 0;
    __syncthreads();
    int n = bcur[chunk]; if (n > CAP) n = CAP;
    const int2* b = bucket + (size_t)chunk * CAP;
    for (int i = threadIdx.x; i < n; i += 1024)
        atomicAdd(&scnt[b[i].y - lo], 1);
    __syncthreads();
    const int lim = N - lo;                      // may exceed CHUNK_N; clip below
    for (int i = threadIdx.x; i < CHUNK_N; i += 1024)
        if (i < lim) counts[lo + i] = scnt[i];
}

// Block-local inclusive scan (Hillis-Steele over 256 entries in LDS).
__global__ __launch_bounds__(256) void scan1(const int* __restrict__ counts,
                                             int* __restrict__ rowstart,
                                             int* __restrict__ bsum) {
    __shared__ int tmp[256];
    int t = threadIdx.x;
    int i = blockIdx.x * 256 + t;
    int v = (i < N) ? counts[i] : 0;
    tmp[t] = v;
    __syncthreads();
#pragma unroll
    for (int off = 1; off < 256; off <<= 1) {
        int a = (t >= off) ? tmp[t - off] : 0;
        __syncthreads();
        tmp[t] += a;
        __syncthreads();
    }
    if (i < N) rowstart[i] = tmp[t] - v;          // exclusive within block
    if (t == 255) bsum[blockIdx.x] = tmp[255];    // block total
}

__global__ __launch_bounds__(512) void scan2(int* __restrict__ bsum) {
    __shared__ int tmp[512];
    int t = threadIdx.x;
    int v = (t < NBLK) ? bsum[t] : 0;
    tmp[t] = v;
    __syncthreads();
#pragma unroll
    for (int off = 1; off < 512; off <<= 1) {
        int a = (t >= off) ? tmp[t - off] : 0;
        __syncthreads();
        tmp[t] += a;
        __syncthreads();
    }
    if (t < NBLK) bsum[t] = tmp[t] - v;           // exclusive block offsets
}

__global__ void scan3(int* __restrict__ rowstart, const int* __restrict__ bsum) {
    int i = blockIdx.x * blockDim.x + threadIdx.x;
    if (i < N) rowstart[i] += bsum[i >> 8];
    if (i == 0) rowstart[N] = E;
}

// Per-chunk CSR fill: one block per chunk, LDS cursors seeded from rowstart,
// sequential bucket read, csr writes confined to a 100KB window emitted by a
// single CU -> single L2 -> lines fill completely. No global atomics.
__global__ __launch_bounds__(1024) void fill2(
        const int* __restrict__ bcur, const int2* __restrict__ bucket,
        const int* __restrict__ rowstart, int* __restrict__ csr) {
    __shared__ int scur[CHUNK_N];
    const int chunk = blockIdx.x;
    const int lo = chunk * CHUNK_N;
    const int lim = N - lo;
    for (int i = threadIdx.x; i < CHUNK_N; i += 1024)
        scur[i] = (i < lim) ? rowstart[lo + i] : 0;
    __syncthreads();
    int n = bcur[chunk]; if (n > CAP) n = CAP;
    const int2* b = bucket + (size_t)chunk * CAP;
    for (int i = threadIdx.x; i < n; i += 1024) {
        int2 sd = b[i];
        int pos = atomicAdd(&scur[sd.y - lo], 1);
        csr[pos] = sd.x;
    }
}

// ---------------- layer 1 transform (MFMA): z1(bf16) = x@W1l^T, r1(f32) = x@W1r^T ----------------
__global__ __launch_bounds__(256) void transform1_mfma(
        const float* __restrict__ x, const float* __restrict__ W1l,
        const float* __restrict__ W1r, unsigned short* __restrict__ z1b,
        float* __restrict__ r1) {
    const int lane = threadIdx.x & 63;
    const int gw = blockIdx.x * 4 + (threadIdx.x >> 6);
    const int q = gw & 1;
    const int r16 = lane & 15;
    const int kgrp = lane >> 4;                  // 0..3

    bf16x8 wf[2][2][4];                          // [mat][coltile][kb]
#pragma unroll
    for (int m = 0; m < 2; ++m) {
        const float* W = m ? W1r : W1l;
#pragma unroll
        for (int c = 0; c < 2; ++c) {
            const float* pw = W + (size_t)(q * 32 + c * 16 + r16) * 128 + kgrp * 8;
#pragma unroll
            for (int kb = 0; kb < 4; ++kb)
                wf[m][c][kb] = load_frag8(pw + kb * 32);
        }
    }

    const int stride = (gridDim.x * 4) >> 1;
    for (int t = gw >> 1; t < NT16; t += stride) {
        const float* px = x + ((size_t)t * 16 + r16) * 128 + kgrp * 8;
        bf16x8 af[4];
#pragma unroll
        for (int kb = 0; kb < 4; ++kb) af[kb] = load_frag8(px + kb * 32);

        f32x4 a00 = {0.f,0.f,0.f,0.f}, a01 = {0.f,0.f,0.f,0.f};
        f32x4 a10 = {0.f,0.f,0.f,0.f}, a11 = {0.f,0.f,0.f,0.f};
#pragma unroll
        for (int kb = 0; kb < 4; ++kb) {
            a00 = __builtin_amdgcn_mfma_f32_16x16x32_bf16(af[kb], wf[0][0][kb], a00, 0, 0, 0);
            a01 = __builtin_amdgcn_mfma_f32_16x16x32_bf16(af[kb], wf[0][1][kb], a01, 0, 0, 0);
            a10 = __builtin_amdgcn_mfma_f32_16x16x32_bf16(af[kb], wf[1][0][kb], a10, 0, 0, 0);
            a11 = __builtin_amdgcn_mfma_f32_16x16x32_bf16(af[kb], wf[1][1][kb], a11, 0, 0, 0);
        }
#pragma unroll
        for (int i = 0; i < 4; ++i) {
            size_t row = (size_t)t * 16 + kgrp * 4 + i;
            z1b[row * 64 + q * 32 +  0 + r16] = (unsigned short)f2bf(a00[i]);
            z1b[row * 64 + q * 32 + 16 + r16] = (unsigned short)f2bf(a01[i]);
            r1[row * 64 + q * 32 +  0 + r16] = a10[i];
            r1[row * 64 + q * 32 + 16 + r16] = a11[i];
        }
    }
}

// ---------------- layer 2 transform (MFMA): z2(bf16) = h@W2l^T, r2(f32) = h@W2r^T ----------------
__global__ __launch_bounds__(256) void transform2_mfma(
        const float* __restrict__ h, const float* __restrict__ W2l,
        const float* __restrict__ W2r, unsigned short* __restrict__ z2b,
        float* __restrict__ r2) {
    const int lane = threadIdx.x & 63;
    const int gw = blockIdx.x * 4 + (threadIdx.x >> 6);
    const int r16 = lane & 15;
    const int kgrp = lane >> 4;

    bf16x8 wf[2][2][2];                          // [mat][coltile][kb]
#pragma unroll
    for (int m = 0; m < 2; ++m) {
        const float* W = m ? W2r : W2l;
#pragma unroll
        for (int c = 0; c < 2; ++c) {
            const float* pw = W + (size_t)(c * 16 + r16) * 64 + kgrp * 8;
#pragma unroll
            for (int kb = 0; kb < 2; ++kb)
                wf[m][c][kb] = load_frag8(pw + kb * 32);
        }
    }

    for (int t = gw; t < NT16; t += gridDim.x * 4) {
        const float* ph = h + ((size_t)t * 16 + r16) * 64 + kgrp * 8;
        bf16x8 af[2];
        af[0] = load_frag8(ph);
        af[1] = load_frag8(ph + 32);

        f32x4 a00 = {0.f,0.f,0.f,0.f}, a01 = {0.f,0.f,0.f,0.f};
        f32x4 a10 = {0.f,0.f,0.f,0.f}, a11 = {0.f,0.f,0.f,0.f};
#pragma unroll
        for (int kb = 0; kb < 2; ++kb) {
            a00 = __builtin_amdgcn_mfma_f32_16x16x32_bf16(af[kb], wf[0][0][kb], a00, 0, 0, 0);
            a01 = __builtin_amdgcn_mfma_f32_16x16x32_bf16(af[kb], wf[0][1][kb], a01, 0, 0, 0);
            a10 = __builtin_amdgcn_mfma_f32_16x16x32_bf16(af[kb], wf[1][0][kb], a10, 0, 0, 0);
            a11 = __builtin_amdgcn_mfma_f32_16x16x32_bf16(af[kb], wf[1][1][kb], a11, 0, 0, 0);
        }
#pragma unroll
        for (int i = 0; i < 4; ++i) {
            size_t row = (size_t)t * 16 + kgrp * 4 + i;
            z2b[row * 32 +  0 + r16] = (unsigned short)f2bf(a00[i]);
            z2b[row * 32 + 16 + r16] = (unsigned short)f2bf(a01[i]);
            r2[row * 32 +  0 + r16] = a10[i];
            r2[row * 32 + 16 + r16] = a11[i];
        }
    }
}

// ---------------- fused CSR-gather aggregation ----------------

// Layer 1: wave per node, lane = feature j (64 feats), bf16 z gather.
__global__ __launch_bounds__(256) void agg1_fused(
        const int* __restrict__ rowstart, const int* __restrict__ csr,
        const unsigned short* __restrict__ z1b, const float* __restrict__ r1,
        const float* __restrict__ b1, float* __restrict__ h) {
    const int n = blockIdx.x * 4 + (threadIdx.x >> 6);
    if (n >= N) return;
    const int j = threadIdx.x & 63;
    const int beg = rowstart[n], end = rowstart[n + 1];
    float s = 0.f;
    int p = beg;
    for (; p + 8 <= end; p += 8) {
        int c0 = csr[p],     c1 = csr[p + 1], c2 = csr[p + 2], c3 = csr[p + 3];
        int c4 = csr[p + 4], c5 = csr[p + 5], c6 = csr[p + 6], c7 = csr[p + 7];
        s += bf2f(z1b[(size_t)c0 * 64 + j]) + bf2f(z1b[(size_t)c1 * 64 + j])
           + bf2f(z1b[(size_t)c2 * 64 + j]) + bf2f(z1b[(size_t)c3 * 64 + j])
           + bf2f(z1b[(size_t)c4 * 64 + j]) + bf2f(z1b[(size_t)c5 * 64 + j])
           + bf2f(z1b[(size_t)c6 * 64 + j]) + bf2f(z1b[(size_t)c7 * 64 + j]);
    }
    for (; p < end; ++p) s += bf2f(z1b[(size_t)csr[p] * 64 + j]);
    float m = (end > beg) ? s / (float)(end - beg) : 0.f;
    size_t o = (size_t)n * 64 + j;
    h[o] = fmaxf(m + b1[j] + r1[o], 0.f);
}

// Layer 2: half-wave per node (32 feats), wave handles 2 nodes.
__global__ __launch_bounds__(256) void agg2_fused(
        const int* __restrict__ rowstart, const int* __restrict__ csr,
        const unsigned short* __restrict__ z2b, const float* __restrict__ r2,
        const float* __restrict__ b2, float* __restrict__ out) {
    const int wid = blockIdx.x * 4 + (threadIdx.x >> 6);
    const int n = wid * 2 + ((threadIdx.x >> 5) & 1);
    if (n >= N) return;
    const int j = threadIdx.x & 31;
    const int beg = rowstart[n], end = rowstart[n + 1];
    float s = 0.f;
    int p = beg;
    for (; p + 4 <= end; p += 4) {
        int c0 = csr[p], c1 = csr[p + 1], c2 = csr[p + 2], c3 = csr[p + 3];
        s += bf2f(z2b[(size_t)c0 * 32 + j]) + bf2f(z2b[(size_t)c1 * 32 + j])
           + bf2f(z2b[(size_t)c2 * 32 + j]) + bf2f(z2b[(size_t)c3 * 32 + j]);
    }
    for (; p < end; ++p) s += bf2f(z2b[(size_t)csr[p] * 32 + j]);
    float m = (end > beg) ? s / (float)(end - beg) : 0.f;
    size_t o = (size_t)n * 32 + j;
    out[o] = m + b2[j] + r2[o];
}

// ---------------- launch ----------------

extern "C" void kernel_launch(void* const* d_in, const int* in_sizes, int n_in,
                              void* d_out, int out_size, void* d_ws, size_t ws_size,
                              hipStream_t stream) {
    const float* x    = (const float*)d_in[0];
    const int*   raw  = (const int*)d_in[1];
    const float* W1l  = (const float*)d_in[2];
    const float* b1   = (const float*)d_in[3];
    const float* W1r  = (const float*)d_in[4];
    const float* W2l  = (const float*)d_in[5];
    const float* b2   = (const float*)d_in[6];
    const float* W2r  = (const float*)d_in[7];
    float* out = (float*)d_out;

    // byte-offset workspace layout
    char* wsb = (char*)d_ws;
    unsigned short* z1b = (unsigned short*)wsb;              // [N*64] bf16 (12.8MB)
    unsigned short* z2b = (unsigned short*)wsb;              // [N*32] overlays z1b
    float* r1 = (float*)(wsb + 16 * 1024 * 1024);            // [N*64] f32 (25.6MB)
    float* r2 = (float*)(wsb + 16 * 1024 * 1024);            // [N*32] overlays r1
    float* h  = (float*)(wsb + 48 * 1024 * 1024);            // [N*64] f32 (25.6MB)
    int2* bucket = (int2*)(wsb + 48 * 1024 * 1024);          // 64 x CAP x 8B (14.3MB)
    // bucket overlays h: buckets die (after fill2) before agg1_fused writes h.

    int* ibase    = (int*)(wsb + 80 * 1024 * 1024);
    int* counts   = ibase;                   // [N]
    int* rowstart = ibase + N;               // [N+1]
    int* bsum     = ibase + 2 * N + 1;       // [512]
    int* csr      = ibase + 2 * N + 1 + 512; // [E]
    int* flag     = csr + E;                 // [1]
    int* bcur     = flag + 1;                // [64]

    detect_dtype<<<1, 256, 0, stream>>>(raw, flag, bcur);
    bucket_edges<<<PA_BLOCKS, 256, 0, stream>>>(raw, flag, bcur, bucket);
    count2<<<NCHUNK, 1024, 0, stream>>>(bcur, bucket, counts);
    scan1<<<NBLK, 256, 0, stream>>>(counts, rowstart, bsum);
    scan2<<<1, 512, 0, stream>>>(bsum);
    scan3<<<NBLK, 256, 0, stream>>>(rowstart, bsum);
    fill2<<<NCHUNK, 1024, 0, stream>>>(bcur, bucket, rowstart, csr);

    transform1_mfma<<<1024, 256, 0, stream>>>(x, W1l, W1r, z1b, r1);
    agg1_fused<<<(N + 3) / 4, 256, 0, stream>>>(rowstart, csr, z1b, r1, b1, h);

    transform2_mfma<<<1024, 256, 0, stream>>>(h, W2l, W2r, z2b, r2);
    agg2_fused<<<(N + 7) / 8, 256, 0, stream>>>(rowstart, csr, z2b, r2, b2, out);
}

// Round 15
// 215.680 us; speedup vs baseline: 1.4965x; 1.0410x over previous
//
#include <hip/hip_runtime.h>

// GraphSAGE 2-layer, N=100000, E=1600000, 128 -> 64 -> 32.
// Round 15: agg kernels rewritten as packed-dword multi-row gathers.
// Round-14 counters: agg1 = 68us, VALUBusy 36%, FETCH 96MB -> latency/issue
// bound on 2B-per-lane gathers (8 rows in flight). New: half-wave (agg1,
// 128B rows) / quarter-wave (agg2, 64B rows) dword gathers -> 2x/4x rows per
// load instruction; shfl_xor folds partials; float2 coalesced epilogue.
// CSR build (bucket + per-chunk LDS counting sort), MFMA transforms
// byte-identical to round 14.

namespace {
constexpr int N = 100000;
constexpr int E = 1600000;
constexpr int NBLK = (N + 255) / 256;           // 391 scan blocks
constexpr int NT16 = N / 16;                    // 6250 node tiles (exact)
constexpr int NCHUNK = 64;                      // 1600 nodes per chunk
constexpr int CHUNK_N = 1600;
constexpr int CAP = 28000;                      // bucket capacity
constexpr int PA_BLOCKS = 256;
constexpr int PER_BLK = E / PA_BLOCKS;          // 6250 edges per block
}

using bf16x8 = __attribute__((ext_vector_type(8))) short;
using f32x4  = __attribute__((ext_vector_type(4))) float;

__device__ __forceinline__ short f2bf(float f) {
    unsigned u = __builtin_bit_cast(unsigned, f);
    u += 0x7FFFu + ((u >> 16) & 1u);            // RNE truncate to bf16
    return (short)(u >> 16);
}

__device__ __forceinline__ bf16x8 load_frag8(const float* __restrict__ p) {
    const float4* p4 = (const float4*)p;
    float4 f0 = p4[0], f1 = p4[1];
    bf16x8 r;
    r[0] = f2bf(f0.x); r[1] = f2bf(f0.y); r[2] = f2bf(f0.z); r[3] = f2bf(f0.w);
    r[4] = f2bf(f1.x); r[5] = f2bf(f1.y); r[6] = f2bf(f1.z); r[7] = f2bf(f1.w);
    return r;
}

// packed bf16 pair -> two floats
__device__ __forceinline__ float pk_lo(unsigned u) {
    return __builtin_bit_cast(float, u << 16);
}
__device__ __forceinline__ float pk_hi(unsigned u) {
    return __builtin_bit_cast(float, u & 0xFFFF0000u);
}

// ---------------- CSR build ----------------

__global__ __launch_bounds__(256) void detect_dtype(const int* __restrict__ raw,
                                                    int* __restrict__ flag,
                                                    int* __restrict__ bcur) {
    if (threadIdx.x < NCHUNK) bcur[threadIdx.x] = 0;
    int any = 0;
#pragma unroll
    for (int k = 0; k < 64; ++k) {
        int i = threadIdx.x + k * 256;          // first 16384 qwords
        any |= raw[2 * i + 1];
    }
    unsigned long long b = __ballot(any != 0);
    __shared__ int acc[4];
    int w = threadIdx.x >> 6;
    if ((threadIdx.x & 63) == 0) acc[w] = (b != 0ULL) ? 1 : 0;
    __syncthreads();
    if (threadIdx.x == 0) *flag = acc[0] | acc[1] | acc[2] | acc[3];
}

__global__ __launch_bounds__(256) void bucket_edges(
        const int* __restrict__ raw, const int* __restrict__ flag,
        int* __restrict__ bcur, int2* __restrict__ bucket) {
    __shared__ int cnt[NCHUNK];
    __shared__ int res[NCHUNK];
    if (threadIdx.x < NCHUNK) cnt[threadIdx.x] = 0;
    __syncthreads();
    const int is32 = *flag;
    const int e0 = blockIdx.x * PER_BLK;
    for (int i = threadIdx.x; i < PER_BLK; i += 256) {
        int e = e0 + i;
        int d = is32 ? raw[E + e] : raw[2 * ((long long)E + e)];
        atomicAdd(&cnt[d / CHUNK_N], 1);
    }
    __syncthreads();
    if (threadIdx.x < NCHUNK) {
        res[threadIdx.x] = atomicAdd(&bcur[threadIdx.x], cnt[threadIdx.x]);
        cnt[threadIdx.x] = 0;
    }
    __syncthreads();
    for (int i = threadIdx.x; i < PER_BLK; i += 256) {
        int e = e0 + i;
        int d, s;
        if (is32) { d = raw[E + e]; s = raw[e]; }
        else      { d = raw[2 * ((long long)E + e)]; s = raw[2 * (long long)e]; }
        int c = d / CHUNK_N;
        int pos = res[c] + atomicAdd(&cnt[c], 1);
        if (pos < CAP) bucket[(size_t)c * CAP + pos] = make_int2(s, d);
    }
}

__global__ __launch_bounds__(1024) void count2(
        const int* __restrict__ bcur, const int2* __restrict__ bucket,
        int* __restrict__ counts) {
    __shared__ int scnt[CHUNK_N];
    const int chunk = blockIdx.x;
    const int lo = chunk * CHUNK_N;
    for (int i = threadIdx.x; i < CHUNK_N; i += 1024) scnt[i] = 0;
    __syncthreads();
    int n = bcur[chunk]; if (n > CAP) n = CAP;
    const int2* b = bucket + (size_t)chunk * CAP;
    for (int i = threadIdx.x; i < n; i += 1024)
        atomicAdd(&scnt[b[i].y - lo], 1);
    __syncthreads();
    const int lim = N - lo;
    for (int i = threadIdx.x; i < CHUNK_N; i += 1024)
        if (i < lim) counts[lo + i] = scnt[i];
}

__global__ __launch_bounds__(256) void scan1(const int* __restrict__ counts,
                                             int* __restrict__ rowstart,
                                             int* __restrict__ bsum) {
    __shared__ int tmp[256];
    int t = threadIdx.x;
    int i = blockIdx.x * 256 + t;
    int v = (i < N) ? counts[i] : 0;
    tmp[t] = v;
    __syncthreads();
#pragma unroll
    for (int off = 1; off < 256; off <<= 1) {
        int a = (t >= off) ? tmp[t - off] : 0;
        __syncthreads();
        tmp[t] += a;
        __syncthreads();
    }
    if (i < N) rowstart[i] = tmp[t] - v;
    if (t == 255) bsum[blockIdx.x] = tmp[255];
}

__global__ __launch_bounds__(512) void scan2(int* __restrict__ bsum) {
    __shared__ int tmp[512];
    int t = threadIdx.x;
    int v = (t < NBLK) ? bsum[t] : 0;
    tmp[t] = v;
    __syncthreads();
#pragma unroll
    for (int off = 1; off < 512; off <<= 1) {
        int a = (t >= off) ? tmp[t - off] : 0;
        __syncthreads();
        tmp[t] += a;
        __syncthreads();
    }
    if (t < NBLK) bsum[t] = tmp[t] - v;
}

__global__ void scan3(int* __restrict__ rowstart, const int* __restrict__ bsum) {
    int i = blockIdx.x * blockDim.x + threadIdx.x;
    if (i < N) rowstart[i] += bsum[i >> 8];
    if (i == 0) rowstart[N] = E;
}

__global__ __launch_bounds__(1024) void fill2(
        const int* __restrict__ bcur, const int2* __restrict__ bucket,
        const int* __restrict__ rowstart, int* __restrict__ csr) {
    __shared__ int scur[CHUNK_N];
    const int chunk = blockIdx.x;
    const int lo = chunk * CHUNK_N;
    const int lim = N - lo;
    for (int i = threadIdx.x; i < CHUNK_N; i += 1024)
        scur[i] = (i < lim) ? rowstart[lo + i] : 0;
    __syncthreads();
    int n = bcur[chunk]; if (n > CAP) n = CAP;
    const int2* b = bucket + (size_t)chunk * CAP;
    for (int i = threadIdx.x; i < n; i += 1024) {
        int2 sd = b[i];
        int pos = atomicAdd(&scur[sd.y - lo], 1);
        csr[pos] = sd.x;
    }
}

// ---------------- layer 1 transform (MFMA) ----------------
__global__ __launch_bounds__(256) void transform1_mfma(
        const float* __restrict__ x, const float* __restrict__ W1l,
        const float* __restrict__ W1r, unsigned short* __restrict__ z1b,
        float* __restrict__ r1) {
    const int lane = threadIdx.x & 63;
    const int gw = blockIdx.x * 4 + (threadIdx.x >> 6);
    const int q = gw & 1;
    const int r16 = lane & 15;
    const int kgrp = lane >> 4;

    bf16x8 wf[2][2][4];
#pragma unroll
    for (int m = 0; m < 2; ++m) {
        const float* W = m ? W1r : W1l;
#pragma unroll
        for (int c = 0; c < 2; ++c) {
            const float* pw = W + (size_t)(q * 32 + c * 16 + r16) * 128 + kgrp * 8;
#pragma unroll
            for (int kb = 0; kb < 4; ++kb)
                wf[m][c][kb] = load_frag8(pw + kb * 32);
        }
    }

    const int stride = (gridDim.x * 4) >> 1;
    for (int t = gw >> 1; t < NT16; t += stride) {
        const float* px = x + ((size_t)t * 16 + r16) * 128 + kgrp * 8;
        bf16x8 af[4];
#pragma unroll
        for (int kb = 0; kb < 4; ++kb) af[kb] = load_frag8(px + kb * 32);

        f32x4 a00 = {0.f,0.f,0.f,0.f}, a01 = {0.f,0.f,0.f,0.f};
        f32x4 a10 = {0.f,0.f,0.f,0.f}, a11 = {0.f,0.f,0.f,0.f};
#pragma unroll
        for (int kb = 0; kb < 4; ++kb) {
            a00 = __builtin_amdgcn_mfma_f32_16x16x32_bf16(af[kb], wf[0][0][kb], a00, 0, 0, 0);
            a01 = __builtin_amdgcn_mfma_f32_16x16x32_bf16(af[kb], wf[0][1][kb], a01, 0, 0, 0);
            a10 = __builtin_amdgcn_mfma_f32_16x16x32_bf16(af[kb], wf[1][0][kb], a10, 0, 0, 0);
            a11 = __builtin_amdgcn_mfma_f32_16x16x32_bf16(af[kb], wf[1][1][kb], a11, 0, 0, 0);
        }
#pragma unroll
        for (int i = 0; i < 4; ++i) {
            size_t row = (size_t)t * 16 + kgrp * 4 + i;
            z1b[row * 64 + q * 32 +  0 + r16] = (unsigned short)f2bf(a00[i]);
            z1b[row * 64 + q * 32 + 16 + r16] = (unsigned short)f2bf(a01[i]);
            r1[row * 64 + q * 32 +  0 + r16] = a10[i];
            r1[row * 64 + q * 32 + 16 + r16] = a11[i];
        }
    }
}

// ---------------- layer 2 transform (MFMA) ----------------
__global__ __launch_bounds__(256) void transform2_mfma(
        const float* __restrict__ h, const float* __restrict__ W2l,
        const float* __restrict__ W2r, unsigned short* __restrict__ z2b,
        float* __restrict__ r2) {
    const int lane = threadIdx.x & 63;
    const int gw = blockIdx.x * 4 + (threadIdx.x >> 6);
    const int r16 = lane & 15;
    const int kgrp = lane >> 4;

    bf16x8 wf[2][2][2];
#pragma unroll
    for (int m = 0; m < 2; ++m) {
        const float* W = m ? W2r : W2l;
#pragma unroll
        for (int c = 0; c < 2; ++c) {
            const float* pw = W + (size_t)(c * 16 + r16) * 64 + kgrp * 8;
#pragma unroll
            for (int kb = 0; kb < 2; ++kb)
                wf[m][c][kb] = load_frag8(pw + kb * 32);
        }
    }

    for (int t = gw; t < NT16; t += gridDim.x * 4) {
        const float* ph = h + ((size_t)t * 16 + r16) * 64 + kgrp * 8;
        bf16x8 af[2];
        af[0] = load_frag8(ph);
        af[1] = load_frag8(ph + 32);

        f32x4 a00 = {0.f,0.f,0.f,0.f}, a01 = {0.f,0.f,0.f,0.f};
        f32x4 a10 = {0.f,0.f,0.f,0.f}, a11 = {0.f,0.f,0.f,0.f};
#pragma unroll
        for (int kb = 0; kb < 2; ++kb) {
            a00 = __builtin_amdgcn_mfma_f32_16x16x32_bf16(af[kb], wf[0][0][kb], a00, 0, 0, 0);
            a01 = __builtin_amdgcn_mfma_f32_16x16x32_bf16(af[kb], wf[0][1][kb], a01, 0, 0, 0);
            a10 = __builtin_amdgcn_mfma_f32_16x16x32_bf16(af[kb], wf[1][0][kb], a10, 0, 0, 0);
            a11 = __builtin_amdgcn_mfma_f32_16x16x32_bf16(af[kb], wf[1][1][kb], a11, 0, 0, 0);
        }
#pragma unroll
        for (int i = 0; i < 4; ++i) {
            size_t row = (size_t)t * 16 + kgrp * 4 + i;
            z2b[row * 32 +  0 + r16] = (unsigned short)f2bf(a00[i]);
            z2b[row * 32 + 16 + r16] = (unsigned short)f2bf(a01[i]);
            r2[row * 32 +  0 + r16] = a10[i];
            r2[row * 32 + 16 + r16] = a11[i];
        }
    }
}

// ---------------- fused CSR-gather aggregation (packed dword) ----------------

// Layer 1: wave per node. Rows are 32 dwords (64 bf16). Half-wave gathers one
// row: lanes 0-31 -> even neighbor, 32-63 -> odd neighbor; lane holds packed
// feat pair (2f, 2f+1). shfl_xor(32) folds halves; lanes 0-31 write float2.
__global__ __launch_bounds__(256) void agg1_fused(
        const int* __restrict__ rowstart, const int* __restrict__ csr,
        const unsigned* __restrict__ z1w, const float* __restrict__ r1,
        const float* __restrict__ b1, float* __restrict__ h) {
    const int n = blockIdx.x * 4 + (threadIdx.x >> 6);
    if (n >= N) return;
    const int lane = threadIdx.x & 63;
    const int half = lane >> 5;                  // 0,1
    const int fl = lane & 31;                    // feat-pair 0..31
    const int beg = rowstart[n], end = rowstart[n + 1];
    float alo = 0.f, ahi = 0.f;
    int p = beg;
    for (; p + 8 <= end; p += 8) {               // 8 rows: 4 paired gathers
        int c0 = csr[p + 0 + half], c1 = csr[p + 2 + half];
        int c2 = csr[p + 4 + half], c3 = csr[p + 6 + half];
        unsigned u0 = z1w[(size_t)c0 * 32 + fl];
        unsigned u1 = z1w[(size_t)c1 * 32 + fl];
        unsigned u2 = z1w[(size_t)c2 * 32 + fl];
        unsigned u3 = z1w[(size_t)c3 * 32 + fl];
        alo += pk_lo(u0) + pk_lo(u1) + pk_lo(u2) + pk_lo(u3);
        ahi += pk_hi(u0) + pk_hi(u1) + pk_hi(u2) + pk_hi(u3);
    }
    for (; p + 2 <= end; p += 2) {
        int c = csr[p + half];
        unsigned u = z1w[(size_t)c * 32 + fl];
        alo += pk_lo(u);
        ahi += pk_hi(u);
    }
    if (p < end && half == 0) {                  // odd tail: half 0 only
        int c = csr[p];
        unsigned u = z1w[(size_t)c * 32 + fl];
        alo += pk_lo(u);
        ahi += pk_hi(u);
    }
    alo += __shfl_xor(alo, 32, 64);
    ahi += __shfl_xor(ahi, 32, 64);
    if (half == 0) {
        float inv = (end > beg) ? 1.0f / (float)(end - beg) : 0.f;
        float2 rv = ((const float2*)r1)[(size_t)n * 32 + fl];
        float2 bv = ((const float2*)b1)[fl];
        float2 o;
        o.x = fmaxf(alo * inv + bv.x + rv.x, 0.f);
        o.y = fmaxf(ahi * inv + bv.y + rv.y, 0.f);
        ((float2*)h)[(size_t)n * 32 + fl] = o;
    }
}

// Layer 2: wave per node. Rows are 16 dwords (32 bf16). Quarter-wave gathers
// one row (4 rows in flight per load batch); two shfl_xor folds; lanes 0-15
// write float2.
__global__ __launch_bounds__(256) void agg2_fused(
        const int* __restrict__ rowstart, const int* __restrict__ csr,
        const unsigned* __restrict__ z2w, const float* __restrict__ r2,
        const float* __restrict__ b2, float* __restrict__ out) {
    const int n = blockIdx.x * 4 + (threadIdx.x >> 6);
    if (n >= N) return;
    const int lane = threadIdx.x & 63;
    const int quad = lane >> 4;                  // 0..3
    const int fl = lane & 15;                    // feat-pair 0..15
    const int beg = rowstart[n], end = rowstart[n + 1];
    float alo = 0.f, ahi = 0.f;
    int p = beg;
    for (; p + 8 <= end; p += 8) {               // 8 rows: 2 quad gathers
        int c0 = csr[p + quad], c1 = csr[p + 4 + quad];
        unsigned u0 = z2w[(size_t)c0 * 16 + fl];
        unsigned u1 = z2w[(size_t)c1 * 16 + fl];
        alo += pk_lo(u0) + pk_lo(u1);
        ahi += pk_hi(u0) + pk_hi(u1);
    }
    for (; p + 4 <= end; p += 4) {
        int c = csr[p + quad];
        unsigned u = z2w[(size_t)c * 16 + fl];
        alo += pk_lo(u);
        ahi += pk_hi(u);
    }
    if (p < end) {                               // tail 1..3 rows
        int r = end - p;
        if (quad < r) {
            int c = csr[p + quad];
            unsigned u = z2w[(size_t)c * 16 + fl];
            alo += pk_lo(u);
            ahi += pk_hi(u);
        }
    }
    alo += __shfl_xor(alo, 16, 64);
    ahi += __shfl_xor(ahi, 16, 64);
    alo += __shfl_xor(alo, 32, 64);
    ahi += __shfl_xor(ahi, 32, 64);
    if (lane < 16) {
        float inv = (end > beg) ? 1.0f / (float)(end - beg) : 0.f;
        float2 rv = ((const float2*)r2)[(size_t)n * 16 + fl];
        float2 bv = ((const float2*)b2)[fl];
        float2 o;
        o.x = alo * inv + bv.x + rv.x;
        o.y = ahi * inv + bv.y + rv.y;
        ((float2*)out)[(size_t)n * 16 + fl] = o;
    }
}

// ---------------- launch ----------------

extern "C" void kernel_launch(void* const* d_in, const int* in_sizes, int n_in,
                              void* d_out, int out_size, void* d_ws, size_t ws_size,
                              hipStream_t stream) {
    const float* x    = (const float*)d_in[0];
    const int*   raw  = (const int*)d_in[1];
    const float* W1l  = (const float*)d_in[2];
    const float* b1   = (const float*)d_in[3];
    const float* W1r  = (const float*)d_in[4];
    const float* W2l  = (const float*)d_in[5];
    const float* b2   = (const float*)d_in[6];
    const float* W2r  = (const float*)d_in[7];
    float* out = (float*)d_out;

    // byte-offset workspace layout
    char* wsb = (char*)d_ws;
    unsigned short* z1b = (unsigned short*)wsb;              // [N*64] bf16 (12.8MB)
    unsigned short* z2b = (unsigned short*)wsb;              // [N*32] overlays z1b
    float* r1 = (float*)(wsb + 16 * 1024 * 1024);            // [N*64] f32 (25.6MB)
    float* r2 = (float*)(wsb + 16 * 1024 * 1024);            // [N*32] overlays r1
    float* h  = (float*)(wsb + 48 * 1024 * 1024);            // [N*64] f32 (25.6MB)
    int2* bucket = (int2*)(wsb + 48 * 1024 * 1024);          // 64 x CAP x 8B (14.3MB)
    // bucket overlays h: buckets die (after fill2) before agg1_fused writes h.

    int* ibase    = (int*)(wsb + 80 * 1024 * 1024);
    int* counts   = ibase;                   // [N]
    int* rowstart = ibase + N;               // [N+1]
    int* bsum     = ibase + 2 * N + 1;       // [512]
    int* csr      = ibase + 2 * N + 1 + 512; // [E]
    int* flag     = csr + E;                 // [1]
    int* bcur     = flag + 1;                // [64]

    detect_dtype<<<1, 256, 0, stream>>>(raw, flag, bcur);
    bucket_edges<<<PA_BLOCKS, 256, 0, stream>>>(raw, flag, bcur, bucket);
    count2<<<NCHUNK, 1024, 0, stream>>>(bcur, bucket, counts);
    scan1<<<NBLK, 256, 0, stream>>>(counts, rowstart, bsum);
    scan2<<<1, 512, 0, stream>>>(bsum);
    scan3<<<NBLK, 256, 0, stream>>>(rowstart, bsum);
    fill2<<<NCHUNK, 1024, 0, stream>>>(bcur, bucket, rowstart, csr);

    transform1_mfma<<<1024, 256, 0, stream>>>(x, W1l, W1r, z1b, r1);
    agg1_fused<<<(N + 3) / 4, 256, 0, stream>>>(rowstart, csr, (const unsigned*)z1b, r1, b1, h);

    transform2_mfma<<<1024, 256, 0, stream>>>(h, W2l, W2r, z2b, r2);
    agg2_fused<<<(N + 3) / 4, 256, 0, stream>>>(rowstart, csr, (const unsigned*)z2b, r2, b2, out);
}